// Round 8
// baseline (353.529 us; speedup 1.0000x reference)
//
#include <hip/hip_runtime.h>

#define DMODEL 1024
#define DSTATE 16
#define DCONV  4
#define DINNER 2048
#define BSZ    2
#define LSEQ   2048
#define MTOT   (BSZ * LSEQ)   // 4096 rows for all GEMMs
#define NCH    64             // scan chunks per sequence
#define LC     (LSEQ / NCH)   // 32 timesteps per chunk
#define LOG2E  1.44269504088896f

typedef unsigned short u16;
typedef __attribute__((ext_vector_type(8))) short short8;           // 8 bf16 (MFMA A/B frag)
typedef __attribute__((ext_vector_type(8))) unsigned short u16x8;   // 16B bf16 chunk
typedef __attribute__((ext_vector_type(4))) float f32x4;            // MFMA C/D frag

__device__ __forceinline__ float silu_f(float v) {
  return v * __builtin_amdgcn_rcpf(1.f + __builtin_amdgcn_exp2f(-v * LOG2E));
}

__device__ __forceinline__ u16 f2bf(float f) {   // RNE f32 -> bf16
  unsigned int u = __float_as_uint(f);
  u += 0x7FFF + ((u >> 16) & 1);
  return (u16)(u >> 16);
}
__device__ __forceinline__ float bf2f(u16 b) { return __uint_as_float(((unsigned int)b) << 16); }

// async global->LDS, 16B/lane; LDS dest = wave-uniform base + lane*16 (m104)
__device__ __forceinline__ void gload_lds16(const u16* g, u16* l) {
  __builtin_amdgcn_global_load_lds((const __attribute__((address_space(1))) unsigned int*)g,
                                   (__attribute__((address_space(3))) unsigned int*)l, 16, 0, 0);
}

// All four f32->bf16 casts in one dispatch (x, W_in, W_dt, W_out), row-major
__global__ __launch_bounds__(256)
void cast4(const float4* __restrict__ s0, ushort4* __restrict__ d0, int n0,
           const float4* __restrict__ s1, ushort4* __restrict__ d1, int n1,
           const float4* __restrict__ s2, ushort4* __restrict__ d2, int n2,
           const float4* __restrict__ s3, ushort4* __restrict__ d3, int n3) {
  int i = blockIdx.x * 256 + threadIdx.x;
  const float4* s; ushort4* d;
  if (i < n0)                { s = s0; d = d0; }
  else if ((i -= n0) < n1)   { s = s1; d = d1; }
  else if ((i -= n1) < n2)   { s = s2; d = d2; }
  else if ((i -= n2) < n3)   { s = s3; d = d3; }
  else return;
  float4 v = s[i];
  ushort4 o = { f2bf(v.x), f2bf(v.y), f2bf(v.z), f2bf(v.w) };
  d[i] = o;
}

// C[M,N] = A[M,K] @ B[N,K]^T, bf16 inputs. 128x128 tile, BK=64, 4 waves,
// 32 MFMA between barriers. LDS 2x16KB, XOR-swizzled (row&7) -> conflict-free.
// GROUP_M=4 panel swizzle. MODE 0: plain; 1: softplus(+bias). OBF: bf16/fp32 C.
template<int MODE, int OBF>
__global__ __launch_bounds__(256)
void hgemm64(const u16* __restrict__ A, const u16* __restrict__ B,
             const float* __restrict__ bias, void* __restrict__ Cv,
             int M, int N, int K) {
  __shared__ u16 As[128 * 64];   // 16 KB
  __shared__ u16 Bs[128 * 64];   // 16 KB
  const int tid  = threadIdx.x;
  const int lane = tid & 63;
  const int w    = tid >> 6;
  const int quad = lane >> 4;
  const int l16  = lane & 15;

  const int nbn = N >> 7, nbm = M >> 7;
  const int pid = blockIdx.x;
  const int npg = 4 * nbn;
  const int fm  = (pid / npg) * 4;
  const int gsz = (nbm - fm < 4) ? (nbm - fm) : 4;
  const int bm  = (fm + (pid % gsz)) << 7;
  const int bn  = ((pid % npg) / gsz) << 7;

  const int wm = (w & 1) * 64;
  const int wn = (w >> 1) * 64;

  const int rseg = lane >> 3;
  const int cd   = (lane & 7) ^ rseg;
  const u16* Ag[4]; const u16* Bg[4]; u16* Al[4]; u16* Bl[4];
#pragma unroll
  for (int s = 0; s < 4; ++s) {
    const int sg = w * 4 + s;
    const int r  = sg * 8 + rseg;
    Ag[s] = A + (size_t)(bm + r) * K + (cd << 3);
    Bg[s] = B + (size_t)(bn + r) * K + (cd << 3);
    Al[s] = &As[sg << 9];
    Bl[s] = &Bs[sg << 9];
  }

  const short8* Afp[4][2];
  const short8* Bfp[4][2];
#pragma unroll
  for (int t = 0; t < 4; ++t) {
    const int ra = wm + 16 * t + l16;
    const int rb = wn + 16 * t + l16;
#pragma unroll
    for (int ks = 0; ks < 2; ++ks) {
      Afp[t][ks] = (const short8*)&As[ra * 64 + (((quad + 4 * ks) ^ (ra & 7)) << 3)];
      Bfp[t][ks] = (const short8*)&Bs[rb * 64 + (((quad + 4 * ks) ^ (rb & 7)) << 3)];
    }
  }

  f32x4 acc[4][4] = {};

  for (int k0 = 0; k0 < K; k0 += 64) {
#pragma unroll
    for (int s = 0; s < 4; ++s) {
      gload_lds16(Ag[s], Al[s]);
      gload_lds16(Bg[s], Bl[s]);
      Ag[s] += 64; Bg[s] += 64;
    }
    __syncthreads();
#pragma unroll
    for (int ks = 0; ks < 2; ++ks) {
      short8 af[4], bf[4];
#pragma unroll
      for (int t = 0; t < 4; ++t) { af[t] = *Afp[t][ks]; bf[t] = *Bfp[t][ks]; }
#pragma unroll
      for (int ti = 0; ti < 4; ++ti)
#pragma unroll
        for (int tj = 0; tj < 4; ++tj)
          acc[ti][tj] = __builtin_amdgcn_mfma_f32_16x16x32_bf16(af[ti], bf[tj],
                                                                acc[ti][tj], 0, 0, 0);
    }
    __syncthreads();
  }

#pragma unroll
  for (int ti = 0; ti < 4; ++ti) {
    const int row0 = bm + wm + 16 * ti + quad * 4;
#pragma unroll
    for (int tj = 0; tj < 4; ++tj) {
      const int col = bn + wn + 16 * tj + l16;
      const float bv = (MODE == 1) ? bias[col] : 0.f;
#pragma unroll
      for (int i = 0; i < 4; ++i) {
        float v = acc[ti][tj][i] + bv;
        if (MODE == 1) v = (v > 20.f) ? v : __logf(1.f + __expf(v));   // softplus
        if (OBF) ((u16*)Cv)[(size_t)(row0 + i) * N + col] = f2bf(v);
        else     ((float*)Cv)[(size_t)(row0 + i) * N + col] = v;
      }
    }
  }
}

// 128x64-tile variant for narrow-N GEMM3 (N=1024): 512 blocks (2/CU) instead
// of 256 (1/CU). 4 waves of 64x32; staging 24 segs (A 16 + B 8), 6 per wave.
__global__ __launch_bounds__(256)
void hgemm_n64(const u16* __restrict__ A, const u16* __restrict__ B,
               float* __restrict__ C, int M, int N, int K) {
  __shared__ u16 As[128 * 64];   // 16 KB
  __shared__ u16 Bs[64 * 64];    //  8 KB
  const int tid  = threadIdx.x;
  const int lane = tid & 63;
  const int w    = tid >> 6;
  const int quad = lane >> 4;
  const int l16  = lane & 15;

  const int nbn = N >> 6, nbm = M >> 7;
  const int pid = blockIdx.x;
  const int npg = 4 * nbn;
  const int fm  = (pid / npg) * 4;
  const int gsz = (nbm - fm < 4) ? (nbm - fm) : 4;
  const int bm  = (fm + (pid % gsz)) << 7;
  const int bn  = ((pid % npg) / gsz) << 6;

  const int wm = (w & 1) * 64;
  const int wn = (w >> 1) * 32;

  const int rseg = lane >> 3;
  const int cd   = (lane & 7) ^ rseg;
  const u16* Gp[6]; u16* Lp[6];
#pragma unroll
  for (int q = 0; q < 6; ++q) {
    const int g = w * 6 + q;
    if (g < 16) {
      const int r = g * 8 + rseg;
      Gp[q] = A + (size_t)(bm + r) * K + (cd << 3);
      Lp[q] = &As[g << 9];
    } else {
      const int r = (g - 16) * 8 + rseg;
      Gp[q] = B + (size_t)(bn + r) * K + (cd << 3);
      Lp[q] = &Bs[(g - 16) << 9];
    }
  }

  const short8* Afp[4][2];
  const short8* Bfp[2][2];
#pragma unroll
  for (int t = 0; t < 4; ++t) {
    const int ra = wm + 16 * t + l16;
#pragma unroll
    for (int ks = 0; ks < 2; ++ks)
      Afp[t][ks] = (const short8*)&As[ra * 64 + (((quad + 4 * ks) ^ (ra & 7)) << 3)];
  }
#pragma unroll
  for (int t = 0; t < 2; ++t) {
    const int rb = wn + 16 * t + l16;
#pragma unroll
    for (int ks = 0; ks < 2; ++ks)
      Bfp[t][ks] = (const short8*)&Bs[rb * 64 + (((quad + 4 * ks) ^ (rb & 7)) << 3)];
  }

  f32x4 acc[4][2] = {};

  for (int k0 = 0; k0 < K; k0 += 64) {
#pragma unroll
    for (int q = 0; q < 6; ++q) { gload_lds16(Gp[q], Lp[q]); Gp[q] += 64; }
    __syncthreads();
#pragma unroll
    for (int ks = 0; ks < 2; ++ks) {
      short8 af[4], bf[2];
#pragma unroll
      for (int t = 0; t < 4; ++t) af[t] = *Afp[t][ks];
#pragma unroll
      for (int t = 0; t < 2; ++t) bf[t] = *Bfp[t][ks];
#pragma unroll
      for (int ti = 0; ti < 4; ++ti)
#pragma unroll
        for (int tj = 0; tj < 2; ++tj)
          acc[ti][tj] = __builtin_amdgcn_mfma_f32_16x16x32_bf16(af[ti], bf[tj],
                                                                acc[ti][tj], 0, 0, 0);
    }
    __syncthreads();
  }

#pragma unroll
  for (int ti = 0; ti < 4; ++ti) {
    const int row0 = bm + wm + 16 * ti + quad * 4;
#pragma unroll
    for (int tj = 0; tj < 2; ++tj) {
      const int col = bn + wn + 16 * tj + l16;
#pragma unroll
      for (int i = 0; i < 4; ++i)
        C[(size_t)(row0 + i) * N + col] = acc[ti][tj][i];
    }
  }
}

// depthwise causal conv1d (taps=4) + bias + SiLU; thread per (t, 8-channel octet)
__global__ __launch_bounds__(256)
void conv_silu(const u16* __restrict__ xz, const float* __restrict__ conv_w,
               const float* __restrict__ conv_b, u16* __restrict__ xact) {
  const int i = blockIdx.x * 256 + threadIdx.x;  // MTOT * 256 octets = 2^20
  const int ko = i & 255;
  const int t  = (i >> 8) & (LSEQ - 1);
  const int b  = i >> 19;
  const int c  = ko << 3;
  float a[8];
  float4 w[8];
#pragma unroll
  for (int j = 0; j < 8; ++j) {
    a[j] = conv_b[c + j];
    w[j] = *(const float4*)(conv_w + (c + j) * DCONV);
  }
#pragma unroll
  for (int k = 0; k < DCONV; ++k) {
    const int tt = t + k - (DCONV - 1);
    if (tt >= 0) {
      const u16x8 v = *(const u16x8*)(xz + ((size_t)(b * LSEQ + tt) << 12) + c);
#pragma unroll
      for (int j = 0; j < 8; ++j)
        a[j] = fmaf(bf2f(v[j]), ((const float*)&w[j])[k], a[j]);
    }
  }
  u16x8 o;
#pragma unroll
  for (int j = 0; j < 8; ++j) o[j] = f2bf(silu_f(a[j]));
  *(u16x8*)(xact + ((size_t)(b * LSEQ + t) << 11) + c) = o;
}

// ---- fused chunked scan: pass1 + tree-combine + pass3 + gate in ONE kernel --
// Block = (batch, 4 channels). Stage all 2048 timesteps of (dt,xact) packed
// into 32 KB LDS (XOR-swizzled: chunk-aliased rows land in distinct banks).
// Thread = (chunk 0..63, ch 0..3). Phase1: local scan -> (sum_dt, h_end[16]).
// Combine: 6-round Kogge-Stone over chunks with operator (sd, H):
//   self∘pred = (sd_s + sd_p, exp2(a2*sd_s)*H_p + H_s)   [exact algebra]
// Phase3: re-scan from h_start, y into LDS; final coalesced gate pass.
__device__ __forceinline__ int swiz(int t, int ch) {
  return (t * 4 + ch) ^ (((t >> 5) & 7) << 2);
}

__global__ __launch_bounds__(256)
void scan_fused(const u16* __restrict__ dtb, const u16* __restrict__ xact,
                const u16* __restrict__ xz, const float* __restrict__ A_log,
                const float* __restrict__ Dp, u16* __restrict__ yg) {
  __shared__ unsigned int stage[LSEQ * 4];   // 32 KB packed (xact<<16 | dt)
  __shared__ float tree[256 * 17];           // 17 KB (sd, H[16]) stride 17
  const int tid = threadIdx.x;
  const int ch  = tid & 3;
  const int ck  = tid >> 2;                  // chunk 0..63
  const int b   = blockIdx.x >> 9;
  const int c   = ((blockIdx.x & 511) << 2) + ch;

  // stage (t,ch): 4 lanes share 8B-contiguous global; per-wave LDS writes
  // are 64 consecutive words ^ uniform XOR -> conflict-free
#pragma unroll 4
  for (int i = 0; i < 32; ++i) {
    const int t = i * 64 + ck;
    const size_t g = ((size_t)(b * LSEQ + t) << 11) + c;
    stage[swiz(t, ch)] = ((unsigned int)xact[g] << 16) | (unsigned int)dtb[g];
  }
  float a2[16];
#pragma unroll
  for (int s = 0; s < 16; ++s)
    a2[s] = -__expf(A_log[c * DSTATE + s]) * LOG2E;
  const float dp = Dp[c];
  __syncthreads();

  // phase 1: local chunk scan from h=0
  float h[16] = {};
  float sd = 0.f;
  const int t0 = ck * LC;
  for (int j = 0; j < LC; j += 2) {
    const unsigned int w0 = stage[swiz(t0 + j, ch)];
    const unsigned int w1 = stage[swiz(t0 + j + 1, ch)];
    const float dt0 = bf2f((u16)w0), xv0 = bf2f((u16)(w0 >> 16));
    const float dt1 = bf2f((u16)w1), xv1 = bf2f((u16)(w1 >> 16));
    const float dx0 = dt0 * xv0, dx1 = dt1 * xv1;
    sd += dt0 + dt1;
#pragma unroll
    for (int s = 0; s < 16; ++s)
      h[s] = fmaf(__builtin_amdgcn_exp2f(dt0 * a2[s]), h[s], dx0);
#pragma unroll
    for (int s = 0; s < 16; ++s)
      h[s] = fmaf(__builtin_amdgcn_exp2f(dt1 * a2[s]), h[s], dx1);
  }

  // Kogge-Stone inclusive scan over 64 chunks (per channel)
  float* ent = &tree[tid * 17];
  ent[0] = sd;
#pragma unroll
  for (int s = 0; s < 16; ++s) ent[1 + s] = h[s];
#pragma unroll
  for (int off = 1; off < 64; off <<= 1) {
    __syncthreads();
    float psd = 0.f, ph[16];
    const bool has = (ck >= off);
    if (has) {
      const float* p = &tree[(tid - 4 * off) * 17];
      psd = p[0];
#pragma unroll
      for (int s = 0; s < 16; ++s) ph[s] = p[1 + s];
    }
    __syncthreads();
    if (has) {
#pragma unroll
      for (int s = 0; s < 16; ++s)
        h[s] = fmaf(__builtin_amdgcn_exp2f(sd * a2[s]), ph[s], h[s]);
      sd += psd;
      ent[0] = sd;
#pragma unroll
      for (int s = 0; s < 16; ++s) ent[1 + s] = h[s];
    }
  }
  __syncthreads();

  // exclusive: h_start = inclusive prefix of chunk ck-1 (chunk 0 -> 0)
  if (ck == 0) {
#pragma unroll
    for (int s = 0; s < 16; ++s) h[s] = 0.f;
  } else {
    const float* p = &tree[(tid - 4) * 17];
#pragma unroll
    for (int s = 0; s < 16; ++s) h[s] = p[1 + s];
  }

  // phase 3: re-scan from h_start; y overwrites the stage word (own-thread word)
  for (int j = 0; j < LC; j += 2) {
    const unsigned int w0 = stage[swiz(t0 + j, ch)];
    const unsigned int w1 = stage[swiz(t0 + j + 1, ch)];
    const float dt0 = bf2f((u16)w0), xv0 = bf2f((u16)(w0 >> 16));
    const float dt1 = bf2f((u16)w1), xv1 = bf2f((u16)(w1 >> 16));
    const float dx0 = dt0 * xv0, dx1 = dt1 * xv1;
    float y0 = 0.f, y1 = 0.f;
#pragma unroll
    for (int s = 0; s < 16; ++s) {
      h[s] = fmaf(__builtin_amdgcn_exp2f(dt0 * a2[s]), h[s], dx0);
      y0 += h[s];
    }
#pragma unroll
    for (int s = 0; s < 16; ++s) {
      h[s] = fmaf(__builtin_amdgcn_exp2f(dt1 * a2[s]), h[s], dx1);
      y1 += h[s];
    }
    stage[swiz(t0 + j, ch)]     = (unsigned int)f2bf(fmaf(dp, xv0, y0));
    stage[swiz(t0 + j + 1, ch)] = (unsigned int)f2bf(fmaf(dp, xv1, y1));
  }
  __syncthreads();

  // gate pass, coalesced (t,ch) mapping: y from LDS, z from global, write yg
#pragma unroll 4
  for (int i = 0; i < 32; ++i) {
    const int t = i * 64 + ck;
    const float y  = bf2f((u16)stage[swiz(t, ch)]);
    const float zv = bf2f(xz[((size_t)(b * LSEQ + t) << 12) + DINNER + c]);
    yg[((size_t)(b * LSEQ + t) << 11) + c] = f2bf(y * silu_f(zv));
  }
}

extern "C" void kernel_launch(void* const* d_in, const int* in_sizes, int n_in,
                              void* d_out, int out_size, void* d_ws, size_t ws_size,
                              hipStream_t stream) {
  const float* x      = (const float*)d_in[0];
  const float* W_in   = (const float*)d_in[1];
  const float* conv_w = (const float*)d_in[2];
  const float* conv_b = (const float*)d_in[3];
  const float* A_log  = (const float*)d_in[4];
  const float* Dp     = (const float*)d_in[5];
  const float* W_dt   = (const float*)d_in[6];
  const float* b_dt   = (const float*)d_in[7];
  const float* W_out  = (const float*)d_in[8];
  float* out = (float*)d_out;

  // workspace layout (~116 MB)
  u16* xz   = (u16*)d_ws;                                // rm [4096,4096] 32 MB
  u16* dtb  = xz   + (size_t)MTOT * 2 * DINNER;          // rm [4096,2048] 16 MB
  u16* xbf  = dtb  + (size_t)MTOT * DINNER;              // x bf16          8 MB
  u16* wibf = xbf  + (size_t)MTOT * DMODEL;              // W_in bf16       8 MB
  u16* wdbf = wibf + (size_t)2 * DINNER * DMODEL;        // W_dt bf16       8 MB
  u16* wobf = wdbf + (size_t)DINNER * DINNER;            // W_out bf16      4 MB
  u16* xact = wobf + (size_t)DMODEL * DINNER;            // x_act bf16     16 MB
  u16* yg   = xact + (size_t)MTOT * DINNER;              // y_gated bf16   16 MB

  const dim3 blk(256);

  // 0) all casts in one dispatch
  const int n0 = MTOT * DMODEL / 4, n1 = 2 * DINNER * DMODEL / 4;
  const int n2 = DINNER * DINNER / 4, n3 = DMODEL * DINNER / 4;
  cast4<<<(n0 + n1 + n2 + n3) / 256, blk, 0, stream>>>(
      (const float4*)x, (ushort4*)xbf, n0,
      (const float4*)W_in, (ushort4*)wibf, n1,
      (const float4*)W_dt, (ushort4*)wdbf, n2,
      (const float4*)W_out, (ushort4*)wobf, n3);

  // 1) xz = x @ W_in^T (bf16 out)
  hgemm64<0, 1><<<(MTOT / 128) * (2 * DINNER / 128), blk, 0, stream>>>(
      xbf, wibf, nullptr, xz, MTOT, 2 * DINNER, DMODEL);
  // 2) x_act = silu(conv(x_proj) + conv_b), bf16
  conv_silu<<<(MTOT * 256) / 256, blk, 0, stream>>>(xz, conv_w, conv_b, xact);
  // 3) dt = softplus(x_act @ W_dt^T + b_dt), bf16 out
  hgemm64<1, 1><<<(MTOT / 128) * (DINNER / 128), blk, 0, stream>>>(
      xact, wdbf, b_dt, dtb, MTOT, DINNER, DINNER);
  // 4) fused chunked scan + D skip + gate (one dispatch)
  scan_fused<<<BSZ * (DINNER / 4), blk, 0, stream>>>(dtb, xact, xz, A_log, Dp, yg);
  // 5) out = y_gated @ W_out^T (fp32 out), 128x64 tiles for N=1024
  hgemm_n64<<<(MTOT / 128) * (DMODEL / 64), blk, 0, stream>>>(
      yg, wobf, out, MTOT, DMODEL, DINNER);
}

// Round 9
// 310.467 us; speedup vs baseline: 1.1387x; 1.1387x over previous
//
#include <hip/hip_runtime.h>

#define DMODEL 1024
#define DSTATE 16
#define DCONV  4
#define DINNER 2048
#define BSZ    2
#define LSEQ   2048
#define MTOT   (BSZ * LSEQ)   // 4096 rows for all GEMMs
#define NCH    64             // scan chunks per sequence
#define LC     (LSEQ / NCH)   // 32 timesteps per chunk
#define LOG2E  1.44269504088896f

typedef unsigned short u16;
typedef __attribute__((ext_vector_type(8))) short short8;           // 8 bf16 (MFMA A/B frag)
typedef __attribute__((ext_vector_type(8))) unsigned short u16x8;   // 16B bf16 chunk
typedef __attribute__((ext_vector_type(4))) float f32x4;            // MFMA C/D frag

__device__ __forceinline__ float silu_f(float v) {
  return v * __builtin_amdgcn_rcpf(1.f + __builtin_amdgcn_exp2f(-v * LOG2E));
}

__device__ __forceinline__ u16 f2bf(float f) {   // RNE f32 -> bf16
  unsigned int u = __float_as_uint(f);
  u += 0x7FFF + ((u >> 16) & 1);
  return (u16)(u >> 16);
}
__device__ __forceinline__ float bf2f(u16 b) { return __uint_as_float(((unsigned int)b) << 16); }

// async global->LDS, 16B/lane; LDS dest = wave-uniform base + lane*16 (m104)
__device__ __forceinline__ void gload_lds16(const u16* g, u16* l) {
  __builtin_amdgcn_global_load_lds((const __attribute__((address_space(1))) unsigned int*)g,
                                   (__attribute__((address_space(3))) unsigned int*)l, 16, 0, 0);
}

// All four f32->bf16 casts in one dispatch (x, W_in, W_dt, W_out), row-major
__global__ __launch_bounds__(256)
void cast4(const float4* __restrict__ s0, ushort4* __restrict__ d0, int n0,
           const float4* __restrict__ s1, ushort4* __restrict__ d1, int n1,
           const float4* __restrict__ s2, ushort4* __restrict__ d2, int n2,
           const float4* __restrict__ s3, ushort4* __restrict__ d3, int n3) {
  int i = blockIdx.x * 256 + threadIdx.x;
  const float4* s; ushort4* d;
  if (i < n0)                { s = s0; d = d0; }
  else if ((i -= n0) < n1)   { s = s1; d = d1; }
  else if ((i -= n1) < n2)   { s = s2; d = d2; }
  else if ((i -= n2) < n3)   { s = s3; d = d3; }
  else return;
  float4 v = s[i];
  ushort4 o = { f2bf(v.x), f2bf(v.y), f2bf(v.z), f2bf(v.w) };
  d[i] = o;
}

// ---- 256x128-tile GEMM (for the big N=4096 GEMM1) ---------------------------
// C[M,N] = A[M,K] @ B[N,K]^T, bf16 in. BK=64, 4 waves, wave-tile 128x64
// (8x4 mfma_16x16x32 => 64 MFMA per wave per barrier pair). LDS 48 KB
// (A 32 + B 16), XOR-swizzle (row&7) -> conflict-free. GROUP_M=4 swizzle.
// OBF: 1 -> bf16 C, 0 -> fp32 C.
template<int OBF>
__global__ __launch_bounds__(256, 2)
void hgemm256(const u16* __restrict__ A, const u16* __restrict__ B,
              void* __restrict__ Cv, int M, int N, int K) {
  __shared__ u16 As[256 * 64];   // 32 KB
  __shared__ u16 Bs[128 * 64];   // 16 KB
  const int tid  = threadIdx.x;
  const int lane = tid & 63;
  const int w    = tid >> 6;
  const int quad = lane >> 4;
  const int l16  = lane & 15;

  const int nbn = N >> 7, nbm = M >> 8;
  const int pid = blockIdx.x;
  const int npg = 4 * nbn;
  const int fm  = (pid / npg) * 4;
  const int gsz = (nbm - fm < 4) ? (nbm - fm) : 4;
  const int bm  = (fm + (pid % gsz)) << 8;
  const int bn  = ((pid % npg) / gsz) << 7;

  const int wm = (w & 1) * 128;
  const int wn = (w >> 1) * 64;

  // Staging: 48 segs of 1KB (8 rows x 128B): segs 0-31 = A (256 rows),
  // 32-47 = B (128 rows). Wave w fills segs 12w..12w+11.
  const int rseg = lane >> 3;
  const int cd   = (lane & 7) ^ rseg;
  const u16* Gp[12]; u16* Lp[12];
#pragma unroll
  for (int q = 0; q < 12; ++q) {
    const int g = w * 12 + q;
    if (g < 32) {
      const int r = g * 8 + rseg;
      Gp[q] = A + (size_t)(bm + r) * K + (cd << 3);
      Lp[q] = &As[g << 9];
    } else {
      const int r = (g - 32) * 8 + rseg;
      Gp[q] = B + (size_t)(bn + r) * K + (cd << 3);
      Lp[q] = &Bs[(g - 32) << 9];
    }
  }

  const short8* Afp[8][2];
  const short8* Bfp[4][2];
#pragma unroll
  for (int t = 0; t < 8; ++t) {
    const int ra = wm + 16 * t + l16;
#pragma unroll
    for (int ks = 0; ks < 2; ++ks)
      Afp[t][ks] = (const short8*)&As[ra * 64 + (((quad + 4 * ks) ^ (ra & 7)) << 3)];
  }
#pragma unroll
  for (int t = 0; t < 4; ++t) {
    const int rb = wn + 16 * t + l16;
#pragma unroll
    for (int ks = 0; ks < 2; ++ks)
      Bfp[t][ks] = (const short8*)&Bs[rb * 64 + (((quad + 4 * ks) ^ (rb & 7)) << 3)];
  }

  f32x4 acc[8][4] = {};

  for (int k0 = 0; k0 < K; k0 += 64) {
#pragma unroll
    for (int q = 0; q < 12; ++q) { gload_lds16(Gp[q], Lp[q]); Gp[q] += 64; }
    __syncthreads();
#pragma unroll
    for (int ks = 0; ks < 2; ++ks) {
      short8 af[8], bf[4];
#pragma unroll
      for (int t = 0; t < 8; ++t) af[t] = *Afp[t][ks];
#pragma unroll
      for (int t = 0; t < 4; ++t) bf[t] = *Bfp[t][ks];
#pragma unroll
      for (int ti = 0; ti < 8; ++ti)
#pragma unroll
        for (int tj = 0; tj < 4; ++tj)
          acc[ti][tj] = __builtin_amdgcn_mfma_f32_16x16x32_bf16(af[ti], bf[tj],
                                                                acc[ti][tj], 0, 0, 0);
    }
    __syncthreads();
  }

  // C/D: col = lane&15, row = quad*4 + reg (m89/m91)
#pragma unroll
  for (int ti = 0; ti < 8; ++ti) {
    const int row0 = bm + wm + 16 * ti + quad * 4;
#pragma unroll
    for (int tj = 0; tj < 4; ++tj) {
      const int col = bn + wn + 16 * tj + l16;
#pragma unroll
      for (int i = 0; i < 4; ++i) {
        const float v = acc[ti][tj][i];
        if (OBF) ((u16*)Cv)[(size_t)(row0 + i) * N + col] = f2bf(v);
        else     ((float*)Cv)[(size_t)(row0 + i) * N + col] = v;
      }
    }
  }
}

// ---- 128x128-tile GEMM (GEMM2) ----------------------------------------------
// MODE 0: plain. MODE 1: softplus(C + bias[col]). OBF: bf16/fp32 C.
template<int MODE, int OBF>
__global__ __launch_bounds__(256)
void hgemm64(const u16* __restrict__ A, const u16* __restrict__ B,
             const float* __restrict__ bias, void* __restrict__ Cv,
             int M, int N, int K) {
  __shared__ u16 As[128 * 64];   // 16 KB
  __shared__ u16 Bs[128 * 64];   // 16 KB
  const int tid  = threadIdx.x;
  const int lane = tid & 63;
  const int w    = tid >> 6;
  const int quad = lane >> 4;
  const int l16  = lane & 15;

  const int nbn = N >> 7, nbm = M >> 7;
  const int pid = blockIdx.x;
  const int npg = 4 * nbn;
  const int fm  = (pid / npg) * 4;
  const int gsz = (nbm - fm < 4) ? (nbm - fm) : 4;
  const int bm  = (fm + (pid % gsz)) << 7;
  const int bn  = ((pid % npg) / gsz) << 7;

  const int wm = (w & 1) * 64;
  const int wn = (w >> 1) * 64;

  const int rseg = lane >> 3;
  const int cd   = (lane & 7) ^ rseg;
  const u16* Ag[4]; const u16* Bg[4]; u16* Al[4]; u16* Bl[4];
#pragma unroll
  for (int s = 0; s < 4; ++s) {
    const int sg = w * 4 + s;
    const int r  = sg * 8 + rseg;
    Ag[s] = A + (size_t)(bm + r) * K + (cd << 3);
    Bg[s] = B + (size_t)(bn + r) * K + (cd << 3);
    Al[s] = &As[sg << 9];
    Bl[s] = &Bs[sg << 9];
  }

  const short8* Afp[4][2];
  const short8* Bfp[4][2];
#pragma unroll
  for (int t = 0; t < 4; ++t) {
    const int ra = wm + 16 * t + l16;
    const int rb = wn + 16 * t + l16;
#pragma unroll
    for (int ks = 0; ks < 2; ++ks) {
      Afp[t][ks] = (const short8*)&As[ra * 64 + (((quad + 4 * ks) ^ (ra & 7)) << 3)];
      Bfp[t][ks] = (const short8*)&Bs[rb * 64 + (((quad + 4 * ks) ^ (rb & 7)) << 3)];
    }
  }

  f32x4 acc[4][4] = {};

  for (int k0 = 0; k0 < K; k0 += 64) {
#pragma unroll
    for (int s = 0; s < 4; ++s) {
      gload_lds16(Ag[s], Al[s]);
      gload_lds16(Bg[s], Bl[s]);
      Ag[s] += 64; Bg[s] += 64;
    }
    __syncthreads();
#pragma unroll
    for (int ks = 0; ks < 2; ++ks) {
      short8 af[4], bf[4];
#pragma unroll
      for (int t = 0; t < 4; ++t) { af[t] = *Afp[t][ks]; bf[t] = *Bfp[t][ks]; }
#pragma unroll
      for (int ti = 0; ti < 4; ++ti)
#pragma unroll
        for (int tj = 0; tj < 4; ++tj)
          acc[ti][tj] = __builtin_amdgcn_mfma_f32_16x16x32_bf16(af[ti], bf[tj],
                                                                acc[ti][tj], 0, 0, 0);
    }
    __syncthreads();
  }

#pragma unroll
  for (int ti = 0; ti < 4; ++ti) {
    const int row0 = bm + wm + 16 * ti + quad * 4;
#pragma unroll
    for (int tj = 0; tj < 4; ++tj) {
      const int col = bn + wn + 16 * tj + l16;
      const float bv = (MODE == 1) ? bias[col] : 0.f;
#pragma unroll
      for (int i = 0; i < 4; ++i) {
        float v = acc[ti][tj][i] + bv;
        if (MODE == 1) v = (v > 20.f) ? v : __logf(1.f + __expf(v));   // softplus
        if (OBF) ((u16*)Cv)[(size_t)(row0 + i) * N + col] = f2bf(v);
        else     ((float*)Cv)[(size_t)(row0 + i) * N + col] = v;
      }
    }
  }
}

// 128x64-tile variant for narrow-N GEMM3 (N=1024): 512 blocks (2/CU).
__global__ __launch_bounds__(256)
void hgemm_n64(const u16* __restrict__ A, const u16* __restrict__ B,
               float* __restrict__ C, int M, int N, int K) {
  __shared__ u16 As[128 * 64];   // 16 KB
  __shared__ u16 Bs[64 * 64];    //  8 KB
  const int tid  = threadIdx.x;
  const int lane = tid & 63;
  const int w    = tid >> 6;
  const int quad = lane >> 4;
  const int l16  = lane & 15;

  const int nbn = N >> 6, nbm = M >> 7;
  const int pid = blockIdx.x;
  const int npg = 4 * nbn;
  const int fm  = (pid / npg) * 4;
  const int gsz = (nbm - fm < 4) ? (nbm - fm) : 4;
  const int bm  = (fm + (pid % gsz)) << 7;
  const int bn  = ((pid % npg) / gsz) << 6;

  const int wm = (w & 1) * 64;
  const int wn = (w >> 1) * 32;

  const int rseg = lane >> 3;
  const int cd   = (lane & 7) ^ rseg;
  const u16* Gp[6]; u16* Lp[6];
#pragma unroll
  for (int q = 0; q < 6; ++q) {
    const int g = w * 6 + q;
    if (g < 16) {
      const int r = g * 8 + rseg;
      Gp[q] = A + (size_t)(bm + r) * K + (cd << 3);
      Lp[q] = &As[g << 9];
    } else {
      const int r = (g - 16) * 8 + rseg;
      Gp[q] = B + (size_t)(bn + r) * K + (cd << 3);
      Lp[q] = &Bs[(g - 16) << 9];
    }
  }

  const short8* Afp[4][2];
  const short8* Bfp[2][2];
#pragma unroll
  for (int t = 0; t < 4; ++t) {
    const int ra = wm + 16 * t + l16;
#pragma unroll
    for (int ks = 0; ks < 2; ++ks)
      Afp[t][ks] = (const short8*)&As[ra * 64 + (((quad + 4 * ks) ^ (ra & 7)) << 3)];
  }
#pragma unroll
  for (int t = 0; t < 2; ++t) {
    const int rb = wn + 16 * t + l16;
#pragma unroll
    for (int ks = 0; ks < 2; ++ks)
      Bfp[t][ks] = (const short8*)&Bs[rb * 64 + (((quad + 4 * ks) ^ (rb & 7)) << 3)];
  }

  f32x4 acc[4][2] = {};

  for (int k0 = 0; k0 < K; k0 += 64) {
#pragma unroll
    for (int q = 0; q < 6; ++q) { gload_lds16(Gp[q], Lp[q]); Gp[q] += 64; }
    __syncthreads();
#pragma unroll
    for (int ks = 0; ks < 2; ++ks) {
      short8 af[4], bf[2];
#pragma unroll
      for (int t = 0; t < 4; ++t) af[t] = *Afp[t][ks];
#pragma unroll
      for (int t = 0; t < 2; ++t) bf[t] = *Bfp[t][ks];
#pragma unroll
      for (int ti = 0; ti < 4; ++ti)
#pragma unroll
        for (int tj = 0; tj < 2; ++tj)
          acc[ti][tj] = __builtin_amdgcn_mfma_f32_16x16x32_bf16(af[ti], bf[tj],
                                                                acc[ti][tj], 0, 0, 0);
    }
    __syncthreads();
  }

#pragma unroll
  for (int ti = 0; ti < 4; ++ti) {
    const int row0 = bm + wm + 16 * ti + quad * 4;
#pragma unroll
    for (int tj = 0; tj < 2; ++tj) {
      const int col = bn + wn + 16 * tj + l16;
#pragma unroll
      for (int i = 0; i < 4; ++i)
        C[(size_t)(row0 + i) * N + col] = acc[ti][tj][i];
    }
  }
}

// depthwise causal conv1d (taps=4) + bias + SiLU; thread per (t, 8-channel octet)
__global__ __launch_bounds__(256)
void conv_silu(const u16* __restrict__ xz, const float* __restrict__ conv_w,
               const float* __restrict__ conv_b, u16* __restrict__ xact) {
  const int i = blockIdx.x * 256 + threadIdx.x;  // MTOT * 256 octets = 2^20
  const int ko = i & 255;
  const int t  = (i >> 8) & (LSEQ - 1);
  const int b  = i >> 19;
  const int c  = ko << 3;
  float a[8];
  float4 w[8];
#pragma unroll
  for (int j = 0; j < 8; ++j) {
    a[j] = conv_b[c + j];
    w[j] = *(const float4*)(conv_w + (c + j) * DCONV);
  }
#pragma unroll
  for (int k = 0; k < DCONV; ++k) {
    const int tt = t + k - (DCONV - 1);
    if (tt >= 0) {
      const u16x8 v = *(const u16x8*)(xz + ((size_t)(b * LSEQ + tt) << 12) + c);
#pragma unroll
      for (int j = 0; j < 8; ++j)
        a[j] = fmaf(bf2f(v[j]), ((const float*)&w[j])[k], a[j]);
    }
  }
  u16x8 o;
#pragma unroll
  for (int j = 0; j < 8; ++j) o[j] = f2bf(silu_f(a[j]));
  *(u16x8*)(xact + ((size_t)(b * LSEQ + t) << 11) + c) = o;
}

// ---- chunked parallel scan (3-kernel form; hbuf in bf16) -------------------

__global__ __launch_bounds__(256, 2)
void scan_pass1(const u16* __restrict__ dtb, const u16* __restrict__ xact,
                const float* __restrict__ A_log,
                u16* __restrict__ hbuf, float* __restrict__ sumdt) {
  const int gid = blockIdx.x * 256 + threadIdx.x;  // 2^18 lanes, c fastest
  const int c  = gid & (DINNER - 1);
  const int ch = (gid >> 11) & (NCH - 1);
  const int b  = gid >> 17;
  float a2[16];
#pragma unroll
  for (int s = 0; s < 16; ++s)
    a2[s] = -__expf(A_log[c * DSTATE + s]) * LOG2E;   // exp(dt*a) = exp2(dt*a2)
  const size_t base = ((size_t)(b * LSEQ + ch * LC) << 11) + c;
  float h[16] = {};
  float sd = 0.f;
  for (int j = 0; j < LC; j += 2) {
    const float dt0 = bf2f(dtb [base + ((size_t)j << 11)]);
    const float xv0 = bf2f(xact[base + ((size_t)j << 11)]);
    const float dt1 = bf2f(dtb [base + ((size_t)(j + 1) << 11)]);
    const float xv1 = bf2f(xact[base + ((size_t)(j + 1) << 11)]);
    const float dx0 = dt0 * xv0, dx1 = dt1 * xv1;
    sd += dt0 + dt1;
#pragma unroll
    for (int s = 0; s < 16; ++s)
      h[s] = fmaf(__builtin_amdgcn_exp2f(dt0 * a2[s]), h[s], dx0);
#pragma unroll
    for (int s = 0; s < 16; ++s)
      h[s] = fmaf(__builtin_amdgcn_exp2f(dt1 * a2[s]), h[s], dx1);
  }
  u16x8* ho = (u16x8*)&hbuf[(((size_t)(b * NCH + ch) * DINNER) + c) << 4];
  u16x8 lo, hi;
#pragma unroll
  for (int s = 0; s < 8; ++s) { lo[s] = f2bf(h[s]); hi[s] = f2bf(h[8 + s]); }
  ho[0] = lo; ho[1] = hi;
  sumdt[(size_t)(b * NCH + ch) * DINNER + c] = sd;
}

__global__ __launch_bounds__(256)
void scan_combine(u16* __restrict__ hbuf, const float* __restrict__ sumdt,
                  const float* __restrict__ A_log) {
  const int gid = blockIdx.x * 256 + threadIdx.x;  // 2^16: b*32768 + c*16 + s
  const int s = gid & 15;
  const int c = (gid >> 4) & (DINNER - 1);
  const int b = gid >> 15;
  const float a2 = -__expf(A_log[c * DSTATE + s]) * LOG2E;
  float h = 0.f;
  for (int k = 0; k < NCH; ++k) {
    const size_t o = (((size_t)(b * NCH + k) * DINNER) + c) * 16 + s;
    const float he = bf2f(hbuf[o]);
    const float sd = sumdt[(size_t)(b * NCH + k) * DINNER + c];
    hbuf[o] = f2bf(h);                    // h_start for chunk k
    h = fmaf(__builtin_amdgcn_exp2f(sd * a2), h, he);
  }
}

// Pass 3: re-scan from h_start; y = sum_s h + Dp*x; gate silu(z); bf16 rm out.
__global__ __launch_bounds__(256, 2)
void scan_pass3(const u16* __restrict__ dtb, const u16* __restrict__ xact,
                const u16* __restrict__ xz, const float* __restrict__ A_log,
                const float* __restrict__ Dp, const u16* __restrict__ hbuf,
                u16* __restrict__ yg) {
  const int gid = blockIdx.x * 256 + threadIdx.x;
  const int c  = gid & (DINNER - 1);
  const int ch = (gid >> 11) & (NCH - 1);
  const int b  = gid >> 17;
  float a2[16];
#pragma unroll
  for (int s = 0; s < 16; ++s)
    a2[s] = -__expf(A_log[c * DSTATE + s]) * LOG2E;
  const float dp = Dp[c];
  float h[16];
  const u16x8* hi = (const u16x8*)&hbuf[(((size_t)(b * NCH + ch) * DINNER) + c) << 4];
  const u16x8 vlo = hi[0], vhi = hi[1];
#pragma unroll
  for (int s = 0; s < 8; ++s) { h[s] = bf2f(vlo[s]); h[8 + s] = bf2f(vhi[s]); }
  const size_t base  = ((size_t)(b * LSEQ + ch * LC) << 11) + c;
  const size_t zbase = ((size_t)(b * LSEQ + ch * LC) << 12) + DINNER + c;
  for (int j = 0; j < LC; j += 2) {
    const float dt0 = bf2f(dtb [base + ((size_t)j << 11)]);
    const float xv0 = bf2f(xact[base + ((size_t)j << 11)]);
    const float zv0 = bf2f(xz[zbase + ((size_t)j << 12)]);
    const float dt1 = bf2f(dtb [base + ((size_t)(j + 1) << 11)]);
    const float xv1 = bf2f(xact[base + ((size_t)(j + 1) << 11)]);
    const float zv1 = bf2f(xz[zbase + ((size_t)(j + 1) << 12)]);
    const float dx0 = dt0 * xv0, dx1 = dt1 * xv1;
    float y0 = 0.f, y1 = 0.f;
#pragma unroll
    for (int s = 0; s < 16; ++s) {
      h[s] = fmaf(__builtin_amdgcn_exp2f(dt0 * a2[s]), h[s], dx0);
      y0 += h[s];
    }
#pragma unroll
    for (int s = 0; s < 16; ++s) {
      h[s] = fmaf(__builtin_amdgcn_exp2f(dt1 * a2[s]), h[s], dx1);
      y1 += h[s];
    }
    y0 = fmaf(dp, xv0, y0);
    y1 = fmaf(dp, xv1, y1);
    yg[base + ((size_t)j << 11)]       = f2bf(y0 * silu_f(zv0));
    yg[base + ((size_t)(j + 1) << 11)] = f2bf(y1 * silu_f(zv1));
  }
}

extern "C" void kernel_launch(void* const* d_in, const int* in_sizes, int n_in,
                              void* d_out, int out_size, void* d_ws, size_t ws_size,
                              hipStream_t stream) {
  const float* x      = (const float*)d_in[0];
  const float* W_in   = (const float*)d_in[1];
  const float* conv_w = (const float*)d_in[2];
  const float* conv_b = (const float*)d_in[3];
  const float* A_log  = (const float*)d_in[4];
  const float* Dp     = (const float*)d_in[5];
  const float* W_dt   = (const float*)d_in[6];
  const float* b_dt   = (const float*)d_in[7];
  const float* W_out  = (const float*)d_in[8];
  float* out = (float*)d_out;

  // workspace layout (~125 MB)
  u16* xz   = (u16*)d_ws;                                // rm [4096,4096] 32 MB
  u16* dtb  = xz   + (size_t)MTOT * 2 * DINNER;          // rm [4096,2048] 16 MB
  u16* xbf  = dtb  + (size_t)MTOT * DINNER;              // x bf16          8 MB
  u16* wibf = xbf  + (size_t)MTOT * DMODEL;              // W_in bf16       8 MB
  u16* wdbf = wibf + (size_t)2 * DINNER * DMODEL;        // W_dt bf16       8 MB
  u16* wobf = wdbf + (size_t)DINNER * DINNER;            // W_out bf16      4 MB
  u16* xact = wobf + (size_t)DMODEL * DINNER;            // x_act bf16     16 MB
  u16* yg   = xact + (size_t)MTOT * DINNER;              // y_gated bf16   16 MB
  u16* hbuf = yg   + (size_t)MTOT * DINNER;              // [B,NCH,D,16] bf16 8 MB
  float* sumdt = (float*)(hbuf + (size_t)BSZ * NCH * DINNER * 16); // f32 1 MB

  const dim3 blk(256);

  // 0) all casts in one dispatch
  const int n0 = MTOT * DMODEL / 4, n1 = 2 * DINNER * DMODEL / 4;
  const int n2 = DINNER * DINNER / 4, n3 = DMODEL * DINNER / 4;
  cast4<<<(n0 + n1 + n2 + n3) / 256, blk, 0, stream>>>(
      (const float4*)x, (ushort4*)xbf, n0,
      (const float4*)W_in, (ushort4*)wibf, n1,
      (const float4*)W_dt, (ushort4*)wdbf, n2,
      (const float4*)W_out, (ushort4*)wobf, n3);

  // 1) xz = x @ W_in^T (bf16 out), 256x128 tiles
  hgemm256<1><<<(MTOT / 256) * (2 * DINNER / 128), blk, 0, stream>>>(
      xbf, wibf, xz, MTOT, 2 * DINNER, DMODEL);
  // 2) x_act = silu(conv(x_proj) + conv_b), bf16
  conv_silu<<<(MTOT * 256) / 256, blk, 0, stream>>>(xz, conv_w, conv_b, xact);
  // 3) dt = softplus(x_act @ W_dt^T + b_dt), bf16 out
  hgemm64<1, 1><<<(MTOT / 128) * (DINNER / 128), blk, 0, stream>>>(
      xact, wdbf, b_dt, dtb, MTOT, DINNER, DINNER);
  // 4) chunked selective scan + D skip + gate (hbuf bf16)
  scan_pass1<<<BSZ * NCH * DINNER / 256, blk, 0, stream>>>(dtb, xact, A_log, hbuf, sumdt);
  scan_combine<<<BSZ * DINNER * 16 / 256, blk, 0, stream>>>(hbuf, sumdt, A_log);
  scan_pass3<<<BSZ * NCH * DINNER / 256, blk, 0, stream>>>(dtb, xact, xz, A_log, Dp, hbuf, yg);
  // 5) out = y_gated @ W_out^T (fp32 out), 128x64 tiles for N=1024
  hgemm_n64<<<(MTOT / 128) * (DMODEL / 64), blk, 0, stream>>>(
      yg, wobf, out, MTOT, DMODEL, DINNER);
}

// Round 10
// 301.586 us; speedup vs baseline: 1.1722x; 1.0294x over previous
//
#include <hip/hip_runtime.h>

#define DMODEL 1024
#define DSTATE 16
#define DCONV  4
#define DINNER 2048
#define BSZ    2
#define LSEQ   2048
#define MTOT   (BSZ * LSEQ)   // 4096 rows for all GEMMs
#define NCH    64             // scan chunks per sequence
#define LC     (LSEQ / NCH)   // 32 timesteps per chunk
#define LOG2E  1.44269504088896f

typedef unsigned short u16;
typedef __attribute__((ext_vector_type(8))) short short8;           // 8 bf16 (MFMA A/B frag)
typedef __attribute__((ext_vector_type(8))) unsigned short u16x8;   // 16B bf16 chunk
typedef __attribute__((ext_vector_type(4))) float f32x4;            // MFMA C/D frag

__device__ __forceinline__ float silu_f(float v) {
  return v * __builtin_amdgcn_rcpf(1.f + __builtin_amdgcn_exp2f(-v * LOG2E));
}

__device__ __forceinline__ u16 f2bf(float f) {   // RNE f32 -> bf16
  unsigned int u = __float_as_uint(f);
  u += 0x7FFF + ((u >> 16) & 1);
  return (u16)(u >> 16);
}
__device__ __forceinline__ float bf2f(u16 b) { return __uint_as_float(((unsigned int)b) << 16); }

// async global->LDS, 16B/lane; LDS dest = wave-uniform base + lane*16 (m104)
__device__ __forceinline__ void gload_lds16(const u16* g, u16* l) {
  __builtin_amdgcn_global_load_lds((const __attribute__((address_space(1))) unsigned int*)g,
                                   (__attribute__((address_space(3))) unsigned int*)l, 16, 0, 0);
}

// All four f32->bf16 casts in one dispatch (x, W_in, W_dt, W_out), row-major
__global__ __launch_bounds__(256)
void cast4(const float4* __restrict__ s0, ushort4* __restrict__ d0, int n0,
           const float4* __restrict__ s1, ushort4* __restrict__ d1, int n1,
           const float4* __restrict__ s2, ushort4* __restrict__ d2, int n2,
           const float4* __restrict__ s3, ushort4* __restrict__ d3, int n3) {
  int i = blockIdx.x * 256 + threadIdx.x;
  const float4* s; ushort4* d;
  if (i < n0)                { s = s0; d = d0; }
  else if ((i -= n0) < n1)   { s = s1; d = d1; }
  else if ((i -= n1) < n2)   { s = s2; d = d2; }
  else if ((i -= n2) < n3)   { s = s3; d = d3; }
  else return;
  float4 v = s[i];
  ushort4 o = { f2bf(v.x), f2bf(v.y), f2bf(v.z), f2bf(v.w) };
  d[i] = o;
}

// ---- 256x128-tile GEMM, BK=64 (GEMM1, K=1024) -------------------------------
// 4 waves, wave-tile 128x64 (64 MFMA per wave per barrier pair). LDS 48 KB.
template<int OBF>
__global__ __launch_bounds__(256, 2)
void hgemm256(const u16* __restrict__ A, const u16* __restrict__ B,
              void* __restrict__ Cv, int M, int N, int K) {
  __shared__ u16 As[256 * 64];   // 32 KB
  __shared__ u16 Bs[128 * 64];   // 16 KB
  const int tid  = threadIdx.x;
  const int lane = tid & 63;
  const int w    = tid >> 6;
  const int quad = lane >> 4;
  const int l16  = lane & 15;

  const int nbn = N >> 7, nbm = M >> 8;
  const int pid = blockIdx.x;
  const int npg = 4 * nbn;
  const int fm  = (pid / npg) * 4;
  const int gsz = (nbm - fm < 4) ? (nbm - fm) : 4;
  const int bm  = (fm + (pid % gsz)) << 8;
  const int bn  = ((pid % npg) / gsz) << 7;

  const int wm = (w & 1) * 128;
  const int wn = (w >> 1) * 64;

  const int rseg = lane >> 3;
  const int cd   = (lane & 7) ^ rseg;
  const u16* Gp[12]; u16* Lp[12];
#pragma unroll
  for (int q = 0; q < 12; ++q) {
    const int g = w * 12 + q;
    if (g < 32) {
      const int r = g * 8 + rseg;
      Gp[q] = A + (size_t)(bm + r) * K + (cd << 3);
      Lp[q] = &As[g << 9];
    } else {
      const int r = (g - 32) * 8 + rseg;
      Gp[q] = B + (size_t)(bn + r) * K + (cd << 3);
      Lp[q] = &Bs[(g - 32) << 9];
    }
  }

  const short8* Afp[8][2];
  const short8* Bfp[4][2];
#pragma unroll
  for (int t = 0; t < 8; ++t) {
    const int ra = wm + 16 * t + l16;
#pragma unroll
    for (int ks = 0; ks < 2; ++ks)
      Afp[t][ks] = (const short8*)&As[ra * 64 + (((quad + 4 * ks) ^ (ra & 7)) << 3)];
  }
#pragma unroll
  for (int t = 0; t < 4; ++t) {
    const int rb = wn + 16 * t + l16;
#pragma unroll
    for (int ks = 0; ks < 2; ++ks)
      Bfp[t][ks] = (const short8*)&Bs[rb * 64 + (((quad + 4 * ks) ^ (rb & 7)) << 3)];
  }

  f32x4 acc[8][4] = {};

  for (int k0 = 0; k0 < K; k0 += 64) {
#pragma unroll
    for (int q = 0; q < 12; ++q) { gload_lds16(Gp[q], Lp[q]); Gp[q] += 64; }
    __syncthreads();
#pragma unroll
    for (int ks = 0; ks < 2; ++ks) {
      short8 af[8], bf[4];
#pragma unroll
      for (int t = 0; t < 8; ++t) af[t] = *Afp[t][ks];
#pragma unroll
      for (int t = 0; t < 4; ++t) bf[t] = *Bfp[t][ks];
#pragma unroll
      for (int ti = 0; ti < 8; ++ti)
#pragma unroll
        for (int tj = 0; tj < 4; ++tj)
          acc[ti][tj] = __builtin_amdgcn_mfma_f32_16x16x32_bf16(af[ti], bf[tj],
                                                                acc[ti][tj], 0, 0, 0);
    }
    __syncthreads();
  }

  // C/D: col = lane&15, row = quad*4 + reg (m89/m91)
#pragma unroll
  for (int ti = 0; ti < 8; ++ti) {
    const int row0 = bm + wm + 16 * ti + quad * 4;
#pragma unroll
    for (int tj = 0; tj < 4; ++tj) {
      const int col = bn + wn + 16 * tj + l16;
#pragma unroll
      for (int i = 0; i < 4; ++i) {
        const float v = acc[ti][tj][i];
        if (OBF) ((u16*)Cv)[(size_t)(row0 + i) * N + col] = f2bf(v);
        else     ((float*)Cv)[(size_t)(row0 + i) * N + col] = v;
      }
    }
  }
}

// ---- 128xBN-tile GEMM, BK=128 (GEMM2 BN=128, GEMM3 BN=64) -------------------
// Grid is 512 blocks for both -> residency was already 2 blocks/CU, so the
// bigger LDS (64/48 KB) costs nothing; barrier pairs halve (32 -> 16).
// Segs are 1 KB = 4 rows x 256 B; phys chunk = data chunk ^ (row&15) ->
// fragment b128 reads hit every bank exactly 8x (the b128 minimum).
// MODE 0: plain. MODE 1: softplus(C + bias[col]). OBF: 1 bf16 C, 0 fp32 C.
template<int MODE, int OBF, int BN>
__global__ __launch_bounds__(256)
void hgemm_bk128(const u16* __restrict__ A, const u16* __restrict__ B,
                 const float* __restrict__ bias, void* __restrict__ Cv,
                 int M, int N, int K) {
  constexpr int ASEG = 32;            // A: 128 rows x 256 B = 32 KB
  constexpr int BSEG = BN / 4;        // B: BN rows x 256 B
  constexpr int SPW  = (ASEG + BSEG) / 4;
  constexpr int BT   = BN / 32;       // B frags per wave (4 or 2)
  __shared__ u16 As[128 * 128];       // 32 KB
  __shared__ u16 Bs[BN * 128];        // 32 or 16 KB
  const int tid  = threadIdx.x;
  const int lane = tid & 63;
  const int w    = tid >> 6;
  const int quad = lane >> 4;
  const int l16  = lane & 15;

  const int nbn = N / BN, nbm = M >> 7;
  const int pid = blockIdx.x;
  const int npg = 4 * nbn;
  const int fm  = (pid / npg) * 4;
  const int gsz = (nbm - fm < 4) ? (nbm - fm) : 4;
  const int bm  = (fm + (pid % gsz)) << 7;
  const int bn  = ((pid % npg) / gsz) * BN;

  const int wm = (w & 1) * 64;
  const int wn = (w >> 1) * (BN / 2);

  // staging: lane -> row_in_seg = l>>4 (4 rows), data chunk = (l&15) ^ (row&15)
  const int rs4 = lane >> 4;
  const u16* Gp[SPW]; u16* Lp[SPW];
#pragma unroll
  for (int q = 0; q < SPW; ++q) {
    const int g = w * SPW + q;
    if (g < ASEG) {
      const int r  = g * 4 + rs4;
      const int cdk = (lane & 15) ^ (r & 15);
      Gp[q] = A + (size_t)(bm + r) * K + (cdk << 3);
      Lp[q] = &As[g << 9];
    } else {
      const int r  = (g - ASEG) * 4 + rs4;
      const int cdk = (lane & 15) ^ (r & 15);
      Gp[q] = B + (size_t)(bn + r) * K + (cdk << 3);
      Lp[q] = &Bs[(g - ASEG) << 9];
    }
  }

  // fragment LDS addr: row*256B + phys*16B, phys = (quad + 4*ks) ^ (row&15)
  const short8* Afp[4][4];
  const short8* Bfp[BT][4];
#pragma unroll
  for (int t = 0; t < 4; ++t) {
    const int ra = wm + 16 * t + l16;
#pragma unroll
    for (int ks = 0; ks < 4; ++ks)
      Afp[t][ks] = (const short8*)&As[ra * 128 + (((quad + 4 * ks) ^ (ra & 15)) << 3)];
  }
#pragma unroll
  for (int t = 0; t < BT; ++t) {
    const int rb = wn + 16 * t + l16;
#pragma unroll
    for (int ks = 0; ks < 4; ++ks)
      Bfp[t][ks] = (const short8*)&Bs[rb * 128 + (((quad + 4 * ks) ^ (rb & 15)) << 3)];
  }

  f32x4 acc[4][BT] = {};

  for (int k0 = 0; k0 < K; k0 += 128) {
#pragma unroll
    for (int q = 0; q < SPW; ++q) { gload_lds16(Gp[q], Lp[q]); Gp[q] += 128; }
    __syncthreads();
#pragma unroll
    for (int ks = 0; ks < 4; ++ks) {
      short8 af[4], bf[BT];
#pragma unroll
      for (int t = 0; t < 4; ++t) af[t] = *Afp[t][ks];
#pragma unroll
      for (int t = 0; t < BT; ++t) bf[t] = *Bfp[t][ks];
#pragma unroll
      for (int ti = 0; ti < 4; ++ti)
#pragma unroll
        for (int tj = 0; tj < BT; ++tj)
          acc[ti][tj] = __builtin_amdgcn_mfma_f32_16x16x32_bf16(af[ti], bf[tj],
                                                                acc[ti][tj], 0, 0, 0);
    }
    __syncthreads();
  }

#pragma unroll
  for (int ti = 0; ti < 4; ++ti) {
    const int row0 = bm + wm + 16 * ti + quad * 4;
#pragma unroll
    for (int tj = 0; tj < BT; ++tj) {
      const int col = bn + wn + 16 * tj + l16;
      const float bv = (MODE == 1) ? bias[col] : 0.f;
#pragma unroll
      for (int i = 0; i < 4; ++i) {
        float v = acc[ti][tj][i] + bv;
        if (MODE == 1) v = (v > 20.f) ? v : __logf(1.f + __expf(v));   // softplus
        if (OBF) ((u16*)Cv)[(size_t)(row0 + i) * N + col] = f2bf(v);
        else     ((float*)Cv)[(size_t)(row0 + i) * N + col] = v;
      }
    }
  }
}

// depthwise causal conv1d (taps=4) + bias + SiLU; thread per (t, 8-channel octet)
__global__ __launch_bounds__(256)
void conv_silu(const u16* __restrict__ xz, const float* __restrict__ conv_w,
               const float* __restrict__ conv_b, u16* __restrict__ xact) {
  const int i = blockIdx.x * 256 + threadIdx.x;  // MTOT * 256 octets = 2^20
  const int ko = i & 255;
  const int t  = (i >> 8) & (LSEQ - 1);
  const int b  = i >> 19;
  const int c  = ko << 3;
  float a[8];
  float4 w[8];
#pragma unroll
  for (int j = 0; j < 8; ++j) {
    a[j] = conv_b[c + j];
    w[j] = *(const float4*)(conv_w + (c + j) * DCONV);
  }
#pragma unroll
  for (int k = 0; k < DCONV; ++k) {
    const int tt = t + k - (DCONV - 1);
    if (tt >= 0) {
      const u16x8 v = *(const u16x8*)(xz + ((size_t)(b * LSEQ + tt) << 12) + c);
#pragma unroll
      for (int j = 0; j < 8; ++j)
        a[j] = fmaf(bf2f(v[j]), ((const float*)&w[j])[k], a[j]);
    }
  }
  u16x8 o;
#pragma unroll
  for (int j = 0; j < 8; ++j) o[j] = f2bf(silu_f(a[j]));
  *(u16x8*)(xact + ((size_t)(b * LSEQ + t) << 11) + c) = o;
}

// ---- chunked parallel scan (3-kernel form; hbuf in bf16) -------------------

__global__ __launch_bounds__(256, 2)
void scan_pass1(const u16* __restrict__ dtb, const u16* __restrict__ xact,
                const float* __restrict__ A_log,
                u16* __restrict__ hbuf, float* __restrict__ sumdt) {
  const int gid = blockIdx.x * 256 + threadIdx.x;  // 2^18 lanes, c fastest
  const int c  = gid & (DINNER - 1);
  const int ch = (gid >> 11) & (NCH - 1);
  const int b  = gid >> 17;
  float a2[16];
#pragma unroll
  for (int s = 0; s < 16; ++s)
    a2[s] = -__expf(A_log[c * DSTATE + s]) * LOG2E;   // exp(dt*a) = exp2(dt*a2)
  const size_t base = ((size_t)(b * LSEQ + ch * LC) << 11) + c;
  float h[16] = {};
  float sd = 0.f;
  for (int j = 0; j < LC; j += 2) {
    const float dt0 = bf2f(dtb [base + ((size_t)j << 11)]);
    const float xv0 = bf2f(xact[base + ((size_t)j << 11)]);
    const float dt1 = bf2f(dtb [base + ((size_t)(j + 1) << 11)]);
    const float xv1 = bf2f(xact[base + ((size_t)(j + 1) << 11)]);
    const float dx0 = dt0 * xv0, dx1 = dt1 * xv1;
    sd += dt0 + dt1;
#pragma unroll
    for (int s = 0; s < 16; ++s)
      h[s] = fmaf(__builtin_amdgcn_exp2f(dt0 * a2[s]), h[s], dx0);
#pragma unroll
    for (int s = 0; s < 16; ++s)
      h[s] = fmaf(__builtin_amdgcn_exp2f(dt1 * a2[s]), h[s], dx1);
  }
  u16x8* ho = (u16x8*)&hbuf[(((size_t)(b * NCH + ch) * DINNER) + c) << 4];
  u16x8 lo, hi;
#pragma unroll
  for (int s = 0; s < 8; ++s) { lo[s] = f2bf(h[s]); hi[s] = f2bf(h[8 + s]); }
  ho[0] = lo; ho[1] = hi;
  sumdt[(size_t)(b * NCH + ch) * DINNER + c] = sd;
}

__global__ __launch_bounds__(256)
void scan_combine(u16* __restrict__ hbuf, const float* __restrict__ sumdt,
                  const float* __restrict__ A_log) {
  const int gid = blockIdx.x * 256 + threadIdx.x;  // 2^16: b*32768 + c*16 + s
  const int s = gid & 15;
  const int c = (gid >> 4) & (DINNER - 1);
  const int b = gid >> 15;
  const float a2 = -__expf(A_log[c * DSTATE + s]) * LOG2E;
  float h = 0.f;
  for (int k = 0; k < NCH; ++k) {
    const size_t o = (((size_t)(b * NCH + k) * DINNER) + c) * 16 + s;
    const float he = bf2f(hbuf[o]);
    const float sd = sumdt[(size_t)(b * NCH + k) * DINNER + c];
    hbuf[o] = f2bf(h);                    // h_start for chunk k
    h = fmaf(__builtin_amdgcn_exp2f(sd * a2), h, he);
  }
}

// Pass 3: re-scan from h_start; y = sum_s h + Dp*x; gate silu(z); bf16 rm out.
__global__ __launch_bounds__(256, 2)
void scan_pass3(const u16* __restrict__ dtb, const u16* __restrict__ xact,
                const u16* __restrict__ xz, const float* __restrict__ A_log,
                const float* __restrict__ Dp, const u16* __restrict__ hbuf,
                u16* __restrict__ yg) {
  const int gid = blockIdx.x * 256 + threadIdx.x;
  const int c  = gid & (DINNER - 1);
  const int ch = (gid >> 11) & (NCH - 1);
  const int b  = gid >> 17;
  float a2[16];
#pragma unroll
  for (int s = 0; s < 16; ++s)
    a2[s] = -__expf(A_log[c * DSTATE + s]) * LOG2E;
  const float dp = Dp[c];
  float h[16];
  const u16x8* hi = (const u16x8*)&hbuf[(((size_t)(b * NCH + ch) * DINNER) + c) << 4];
  const u16x8 vlo = hi[0], vhi = hi[1];
#pragma unroll
  for (int s = 0; s < 8; ++s) { h[s] = bf2f(vlo[s]); h[8 + s] = bf2f(vhi[s]); }
  const size_t base  = ((size_t)(b * LSEQ + ch * LC) << 11) + c;
  const size_t zbase = ((size_t)(b * LSEQ + ch * LC) << 12) + DINNER + c;
  for (int j = 0; j < LC; j += 2) {
    const float dt0 = bf2f(dtb [base + ((size_t)j << 11)]);
    const float xv0 = bf2f(xact[base + ((size_t)j << 11)]);
    const float zv0 = bf2f(xz[zbase + ((size_t)j << 12)]);
    const float dt1 = bf2f(dtb [base + ((size_t)(j + 1) << 11)]);
    const float xv1 = bf2f(xact[base + ((size_t)(j + 1) << 11)]);
    const float zv1 = bf2f(xz[zbase + ((size_t)(j + 1) << 12)]);
    const float dx0 = dt0 * xv0, dx1 = dt1 * xv1;
    float y0 = 0.f, y1 = 0.f;
#pragma unroll
    for (int s = 0; s < 16; ++s) {
      h[s] = fmaf(__builtin_amdgcn_exp2f(dt0 * a2[s]), h[s], dx0);
      y0 += h[s];
    }
#pragma unroll
    for (int s = 0; s < 16; ++s) {
      h[s] = fmaf(__builtin_amdgcn_exp2f(dt1 * a2[s]), h[s], dx1);
      y1 += h[s];
    }
    y0 = fmaf(dp, xv0, y0);
    y1 = fmaf(dp, xv1, y1);
    yg[base + ((size_t)j << 11)]       = f2bf(y0 * silu_f(zv0));
    yg[base + ((size_t)(j + 1) << 11)] = f2bf(y1 * silu_f(zv1));
  }
}

extern "C" void kernel_launch(void* const* d_in, const int* in_sizes, int n_in,
                              void* d_out, int out_size, void* d_ws, size_t ws_size,
                              hipStream_t stream) {
  const float* x      = (const float*)d_in[0];
  const float* W_in   = (const float*)d_in[1];
  const float* conv_w = (const float*)d_in[2];
  const float* conv_b = (const float*)d_in[3];
  const float* A_log  = (const float*)d_in[4];
  const float* Dp     = (const float*)d_in[5];
  const float* W_dt   = (const float*)d_in[6];
  const float* b_dt   = (const float*)d_in[7];
  const float* W_out  = (const float*)d_in[8];
  float* out = (float*)d_out;

  // workspace layout (~125 MB)
  u16* xz   = (u16*)d_ws;                                // rm [4096,4096] 32 MB
  u16* dtb  = xz   + (size_t)MTOT * 2 * DINNER;          // rm [4096,2048] 16 MB
  u16* xbf  = dtb  + (size_t)MTOT * DINNER;              // x bf16          8 MB
  u16* wibf = xbf  + (size_t)MTOT * DMODEL;              // W_in bf16       8 MB
  u16* wdbf = wibf + (size_t)2 * DINNER * DMODEL;        // W_dt bf16       8 MB
  u16* wobf = wdbf + (size_t)DINNER * DINNER;            // W_out bf16      4 MB
  u16* xact = wobf + (size_t)DMODEL * DINNER;            // x_act bf16     16 MB
  u16* yg   = xact + (size_t)MTOT * DINNER;              // y_gated bf16   16 MB
  u16* hbuf = yg   + (size_t)MTOT * DINNER;              // [B,NCH,D,16] bf16 8 MB
  float* sumdt = (float*)(hbuf + (size_t)BSZ * NCH * DINNER * 16); // f32 1 MB

  const dim3 blk(256);

  // 0) all casts in one dispatch
  const int n0 = MTOT * DMODEL / 4, n1 = 2 * DINNER * DMODEL / 4;
  const int n2 = DINNER * DINNER / 4, n3 = DMODEL * DINNER / 4;
  cast4<<<(n0 + n1 + n2 + n3) / 256, blk, 0, stream>>>(
      (const float4*)x, (ushort4*)xbf, n0,
      (const float4*)W_in, (ushort4*)wibf, n1,
      (const float4*)W_dt, (ushort4*)wdbf, n2,
      (const float4*)W_out, (ushort4*)wobf, n3);

  // 1) xz = x @ W_in^T (bf16 out), 256x128 tiles, BK=64
  hgemm256<1><<<(MTOT / 256) * (2 * DINNER / 128), blk, 0, stream>>>(
      xbf, wibf, xz, MTOT, 2 * DINNER, DMODEL);
  // 2) x_act = silu(conv(x_proj) + conv_b), bf16
  conv_silu<<<(MTOT * 256) / 256, blk, 0, stream>>>(xz, conv_w, conv_b, xact);
  // 3) dt = softplus(x_act @ W_dt^T + b_dt), bf16 out; 128x128 tiles, BK=128
  hgemm_bk128<1, 1, 128><<<(MTOT / 128) * (DINNER / 128), blk, 0, stream>>>(
      xact, wdbf, b_dt, dtb, MTOT, DINNER, DINNER);
  // 4) chunked selective scan + D skip + gate (hbuf bf16)
  scan_pass1<<<BSZ * NCH * DINNER / 256, blk, 0, stream>>>(dtb, xact, A_log, hbuf, sumdt);
  scan_combine<<<BSZ * DINNER * 16 / 256, blk, 0, stream>>>(hbuf, sumdt, A_log);
  scan_pass3<<<BSZ * NCH * DINNER / 256, blk, 0, stream>>>(dtb, xact, xz, A_log, Dp, hbuf, yg);
  // 5) out = y_gated @ W_out^T (fp32 out), 128x64 tiles, BK=128
  hgemm_bk128<0, 0, 64><<<(MTOT / 128) * (DMODEL / 64), blk, 0, stream>>>(
      yg, wobf, nullptr, out, MTOT, DMODEL, DINNER);
}